// Round 1
// baseline (1950.430 us; speedup 1.0000x reference)
//
#include <hip/hip_runtime.h>

// Monarch attention, B=4 H=16 N=8192 D=64, b=128, m=64, T=3. fp32 throughout.
// ws layout (floats): qbar[64*128*64*64] | kbar[64*128*64*64] | kbar0[64*64*64]
// d_out doubles as the Vbar buffer (step-2 R-kernel writes it, out-kernel
// reads-then-overwrites it block-locally).

#define BH   64     // B*H
#define NTOK 8192   // N
#define DD   64     // D
#define MM   64     // m = N/b
#define BBS  128    // b

__device__ __forceinline__ float red16_max(float v){
    v = fmaxf(v, __shfl_xor(v, 1));
    v = fmaxf(v, __shfl_xor(v, 2));
    v = fmaxf(v, __shfl_xor(v, 4));
    v = fmaxf(v, __shfl_xor(v, 8));
    return v;
}
__device__ __forceinline__ float red16_sum(float v){
    v += __shfl_xor(v, 1);
    v += __shfl_xor(v, 2);
    v += __shfl_xor(v, 4);
    v += __shfl_xor(v, 8);
    return v;
}

// ---- Kbar0[bh][k][d] = mean over l' of K[bh][k*b+l'][d] ----
__global__ __launch_bounds__(256) void kbar0_kernel(const float* __restrict__ K,
                                                    float* __restrict__ kbar0){
    const int k = blockIdx.x, bh = blockIdx.y;
    const int t = threadIdx.x;
    const int d = t & 63, p = t >> 6;
    __shared__ float part[4][64];
    const float* base = K + ((size_t)bh*NTOK + (size_t)k*BBS)*DD + d;
    float s = 0.f;
    for(int lp = p*32; lp < p*32 + 32; ++lp) s += base[(size_t)lp*DD];
    part[p][d] = s;
    __syncthreads();
    if(t < 64){
        float tot = part[0][t] + part[1][t] + part[2][t] + part[3][t];
        kbar0[((size_t)bh*MM + k)*DD + t] = tot * (1.0f/128.0f);
    }
}

// ---- L-step: per (bh,l). S=Q_l Kbar_l^T, softmax_k -> L (LDS), Qbar out ----
__global__ __launch_bounds__(256) void l_kernel(const float* __restrict__ Q,
                                                const float* __restrict__ kbar,
                                                int mode, float* __restrict__ qbar){
    const int l = blockIdx.x, bh = blockIdx.y;
    const int t = threadIdx.x;
    __shared__ float sQ[64*65];
    __shared__ float sK[64*65];
    __shared__ float sL[64*65];
    #pragma unroll
    for(int j=0;j<4;++j){
        int f = j*256 + t;
        int i = f >> 4, d = (f & 15) << 2;
        float4 v = *(const float4*)(Q + ((size_t)bh*NTOK + (size_t)i*BBS + l)*DD + d);
        float* p = &sQ[i*65 + d];
        p[0]=v.x; p[1]=v.y; p[2]=v.z; p[3]=v.w;
    }
    const float* kb = mode ? (kbar + ((size_t)bh*BBS + l)*(size_t)(MM*DD))
                           : (kbar + (size_t)bh*(size_t)(MM*DD));
    #pragma unroll
    for(int j=0;j<4;++j){
        int f = j*256 + t;
        int k = f >> 4, d = (f & 15) << 2;
        float4 v = *(const float4*)(kb + k*DD + d);
        float* p = &sK[k*65 + d];
        p[0]=v.x; p[1]=v.y; p[2]=v.z; p[3]=v.w;
    }
    __syncthreads();
    const int i0 = (t >> 4) << 2, k0 = (t & 15) << 2;
    float acc[4][4] = {};
    for(int d=0; d<64; ++d){
        float a[4], bb[4];
        #pragma unroll
        for(int r=0;r<4;++r) a[r] = sQ[(i0+r)*65 + d];
        #pragma unroll
        for(int c=0;c<4;++c) bb[c] = sK[(k0+c)*65 + d];
        #pragma unroll
        for(int r=0;r<4;++r)
            #pragma unroll
            for(int c=0;c<4;++c) acc[r][c] = fmaf(a[r], bb[c], acc[r][c]);
    }
    #pragma unroll
    for(int r=0;r<4;++r){
        float mx = -3.4e38f;
        #pragma unroll
        for(int c=0;c<4;++c){ acc[r][c] *= 0.125f; mx = fmaxf(mx, acc[r][c]); }
        mx = red16_max(mx);
        float s = 0.f;
        #pragma unroll
        for(int c=0;c<4;++c){ acc[r][c] = __expf(acc[r][c] - mx); s += acc[r][c]; }
        s = red16_sum(s);
        float inv = 1.0f / s;
        #pragma unroll
        for(int c=0;c<4;++c) sL[(i0+r)*65 + k0 + c] = acc[r][c] * inv;
    }
    __syncthreads();
    // Qbar[k][d] = (sum_i L[i][k] Q[i][d]) / (w[k]+eps);  k-group = i0, d-group = d0
    const int d0 = (t & 15) << 2;
    float acc2[4][4] = {};
    float w4[4] = {0.f,0.f,0.f,0.f};
    for(int i=0;i<64;++i){
        float a[4], bb[4];
        #pragma unroll
        for(int r=0;r<4;++r) a[r] = sL[i*65 + i0 + r];
        #pragma unroll
        for(int c=0;c<4;++c) bb[c] = sQ[i*65 + d0 + c];
        #pragma unroll
        for(int r=0;r<4;++r){
            w4[r] += a[r];
            #pragma unroll
            for(int c=0;c<4;++c) acc2[r][c] = fmaf(a[r], bb[c], acc2[r][c]);
        }
    }
    float* qb = qbar + ((size_t)bh*BBS + l)*(size_t)(MM*DD);
    #pragma unroll
    for(int r=0;r<4;++r){
        float invw = 1.0f/(w4[r] + 1e-6f);
        float4 v = make_float4(acc2[r][0]*invw, acc2[r][1]*invw,
                               acc2[r][2]*invw, acc2[r][3]*invw);
        *(float4*)(qb + (i0+r)*DD + d0) = v;
    }
}

// ---- R-step: per (bh,k,half). S=Qbar_k K_k^T, softmax_{l'} -> R (LDS),
//      out = R @ K  (kbar layout)  or  R @ V  (token layout = Vbar in d_out) ----
__global__ __launch_bounds__(256) void r_kernel(const float* __restrict__ qbar,
                                                const float* __restrict__ K,
                                                const float* __restrict__ V,
                                                float* __restrict__ outp, int outTok){
    const int half = blockIdx.x, k = blockIdx.y, bh = blockIdx.z;
    const int t = threadIdx.x;
    __shared__ float sX[128*65];
    __shared__ float uni[64*129];   // Qbar view (stride 65) then R view (stride 129)
    #pragma unroll
    for(int j=0;j<8;++j){
        int f = j*256 + t;
        int lp = f >> 4, d = (f & 15) << 2;
        float4 v = *(const float4*)(K + ((size_t)bh*NTOK + (size_t)k*BBS + lp)*DD + d);
        float* p = &sX[lp*65 + d];
        p[0]=v.x; p[1]=v.y; p[2]=v.z; p[3]=v.w;
    }
    #pragma unroll
    for(int j=0;j<4;++j){
        int f = j*256 + t;
        int lq = f >> 4, d = (f & 15) << 2;
        float4 v = *(const float4*)(qbar + (((size_t)bh*BBS + half*64 + lq)*(size_t)MM + k)*DD + d);
        float* p = &uni[lq*65 + d];
        p[0]=v.x; p[1]=v.y; p[2]=v.z; p[3]=v.w;
    }
    __syncthreads();
    const int lr0 = (t >> 4) << 2, h = t & 15;
    float acc[4][8] = {};
    for(int d=0; d<64; ++d){
        float a[4], bb[8];
        #pragma unroll
        for(int r=0;r<4;++r) a[r] = uni[(lr0+r)*65 + d];
        #pragma unroll
        for(int c=0;c<8;++c) bb[c] = sX[(h + 16*c)*65 + d];
        #pragma unroll
        for(int r=0;r<4;++r)
            #pragma unroll
            for(int c=0;c<8;++c) acc[r][c] = fmaf(a[r], bb[c], acc[r][c]);
    }
    __syncthreads();   // everyone done reading uni(Qbar) and sX(K)
    #pragma unroll
    for(int r=0;r<4;++r){
        float mx = -3.4e38f;
        #pragma unroll
        for(int c=0;c<8;++c){ acc[r][c] *= 0.125f; mx = fmaxf(mx, acc[r][c]); }
        mx = red16_max(mx);
        float s = 0.f;
        #pragma unroll
        for(int c=0;c<8;++c){ acc[r][c] = __expf(acc[r][c] - mx); s += acc[r][c]; }
        s = red16_sum(s);
        float inv = 1.0f / s;
        #pragma unroll
        for(int c=0;c<8;++c) uni[(lr0+r)*129 + h + 16*c] = acc[r][c] * inv;
    }
    if(V){  // last step: second operand is V, overwrite sX
        #pragma unroll
        for(int j=0;j<8;++j){
            int f = j*256 + t;
            int lp = f >> 4, d = (f & 15) << 2;
            float4 v = *(const float4*)(V + ((size_t)bh*NTOK + (size_t)k*BBS + lp)*DD + d);
            float* p = &sX[lp*65 + d];
            p[0]=v.x; p[1]=v.y; p[2]=v.z; p[3]=v.w;
        }
    }
    __syncthreads();
    const int d0 = (t & 15) << 2;
    float acc2[4][4] = {};
    for(int lp=0; lp<128; ++lp){
        float a[4], bb[4];
        #pragma unroll
        for(int r=0;r<4;++r) a[r] = uni[(lr0+r)*129 + lp];
        #pragma unroll
        for(int c=0;c<4;++c) bb[c] = sX[lp*65 + d0 + c];
        #pragma unroll
        for(int r=0;r<4;++r)
            #pragma unroll
            for(int c=0;c<4;++c) acc2[r][c] = fmaf(a[r], bb[c], acc2[r][c]);
    }
    if(outTok){
        #pragma unroll
        for(int r=0;r<4;++r){
            float4 v = make_float4(acc2[r][0],acc2[r][1],acc2[r][2],acc2[r][3]);
            *(float4*)(outp + ((size_t)bh*NTOK + (size_t)k*BBS + half*64 + lr0 + r)*DD + d0) = v;
        }
    } else {
        #pragma unroll
        for(int r=0;r<4;++r){
            float4 v = make_float4(acc2[r][0],acc2[r][1],acc2[r][2],acc2[r][3]);
            *(float4*)(outp + (((size_t)bh*BBS + half*64 + lr0 + r)*(size_t)MM + k)*DD + d0) = v;
        }
    }
}

// ---- Out: per (bh,l). Recompute L3 from (Q, Kbar2); out_l = L3 @ Vbar_l (in d_out) ----
__global__ __launch_bounds__(256) void out_kernel(const float* __restrict__ Q,
                                                  const float* __restrict__ kbar,
                                                  float* __restrict__ out){
    const int l = blockIdx.x, bh = blockIdx.y;
    const int t = threadIdx.x;
    __shared__ float sQ[64*65];
    __shared__ float sK[64*65];
    __shared__ float sL[64*65];
    __shared__ float sV[64*65];
    #pragma unroll
    for(int j=0;j<4;++j){
        int f = j*256 + t;
        int i = f >> 4, d = (f & 15) << 2;
        float4 v = *(const float4*)(Q + ((size_t)bh*NTOK + (size_t)i*BBS + l)*DD + d);
        float* p = &sQ[i*65 + d];
        p[0]=v.x; p[1]=v.y; p[2]=v.z; p[3]=v.w;
    }
    const float* kb = kbar + ((size_t)bh*BBS + l)*(size_t)(MM*DD);
    #pragma unroll
    for(int j=0;j<4;++j){
        int f = j*256 + t;
        int kk = f >> 4, d = (f & 15) << 2;
        float4 v = *(const float4*)(kb + kk*DD + d);
        float* p = &sK[kk*65 + d];
        p[0]=v.x; p[1]=v.y; p[2]=v.z; p[3]=v.w;
    }
    #pragma unroll
    for(int j=0;j<4;++j){   // Vbar_l lives in d_out at token (kk*b + l)
        int f = j*256 + t;
        int kk = f >> 4, d = (f & 15) << 2;
        float4 v = *(const float4*)(out + ((size_t)bh*NTOK + (size_t)kk*BBS + l)*DD + d);
        float* p = &sV[kk*65 + d];
        p[0]=v.x; p[1]=v.y; p[2]=v.z; p[3]=v.w;
    }
    __syncthreads();
    const int i0 = (t >> 4) << 2, k0 = (t & 15) << 2;
    float acc[4][4] = {};
    for(int d=0; d<64; ++d){
        float a[4], bb[4];
        #pragma unroll
        for(int r=0;r<4;++r) a[r] = sQ[(i0+r)*65 + d];
        #pragma unroll
        for(int c=0;c<4;++c) bb[c] = sK[(k0+c)*65 + d];
        #pragma unroll
        for(int r=0;r<4;++r)
            #pragma unroll
            for(int c=0;c<4;++c) acc[r][c] = fmaf(a[r], bb[c], acc[r][c]);
    }
    #pragma unroll
    for(int r=0;r<4;++r){
        float mx = -3.4e38f;
        #pragma unroll
        for(int c=0;c<4;++c){ acc[r][c] *= 0.125f; mx = fmaxf(mx, acc[r][c]); }
        mx = red16_max(mx);
        float s = 0.f;
        #pragma unroll
        for(int c=0;c<4;++c){ acc[r][c] = __expf(acc[r][c] - mx); s += acc[r][c]; }
        s = red16_sum(s);
        float inv = 1.0f / s;
        #pragma unroll
        for(int c=0;c<4;++c) sL[(i0+r)*65 + k0 + c] = acc[r][c] * inv;
    }
    __syncthreads();
    const int d0 = (t & 15) << 2;
    float acc2[4][4] = {};
    for(int kk=0; kk<64; ++kk){
        float a[4], bb[4];
        #pragma unroll
        for(int r=0;r<4;++r) a[r] = sL[(i0+r)*65 + kk];
        #pragma unroll
        for(int c=0;c<4;++c) bb[c] = sV[kk*65 + d0 + c];
        #pragma unroll
        for(int r=0;r<4;++r)
            #pragma unroll
            for(int c=0;c<4;++c) acc2[r][c] = fmaf(a[r], bb[c], acc2[r][c]);
    }
    #pragma unroll
    for(int r=0;r<4;++r){
        float4 v = make_float4(acc2[r][0],acc2[r][1],acc2[r][2],acc2[r][3]);
        *(float4*)(out + ((size_t)bh*NTOK + (size_t)(i0+r)*BBS + l)*DD + d0) = v;
    }
}

extern "C" void kernel_launch(void* const* d_in, const int* in_sizes, int n_in,
                              void* d_out, int out_size, void* d_ws, size_t ws_size,
                              hipStream_t stream){
    const float* Q = (const float*)d_in[0];
    const float* K = (const float*)d_in[1];
    const float* V = (const float*)d_in[2];
    float* out = (float*)d_out;
    const size_t big = (size_t)BH * BBS * MM * DD;   // 33554432 floats
    float* qbar  = (float*)d_ws;
    float* kbar  = qbar + big;
    float* kbar0 = kbar + big;                       // total ~257 MiB

    kbar0_kernel<<<dim3(MM, BH), 256, 0, stream>>>(K, kbar0);
    // step 0
    l_kernel<<<dim3(BBS, BH), 256, 0, stream>>>(Q, kbar0, 0, qbar);
    r_kernel<<<dim3(2, MM, BH), 256, 0, stream>>>(qbar, K, nullptr, kbar, 0);
    // step 1
    l_kernel<<<dim3(BBS, BH), 256, 0, stream>>>(Q, kbar, 1, qbar);
    r_kernel<<<dim3(2, MM, BH), 256, 0, stream>>>(qbar, K, nullptr, kbar, 0);
    // step 2
    l_kernel<<<dim3(BBS, BH), 256, 0, stream>>>(Q, kbar, 1, qbar);
    r_kernel<<<dim3(2, MM, BH), 256, 0, stream>>>(qbar, K, V, out, 1);   // Vbar -> d_out
    // epilogue: recompute L3, out = L3 @ Vbar (in-place on d_out)
    out_kernel<<<dim3(BBS, BH), 256, 0, stream>>>(Q, kbar, out);
}

// Round 2
// 1289.831 us; speedup vs baseline: 1.5122x; 1.5122x over previous
//
#include <hip/hip_runtime.h>
#include <stdint.h>

// Monarch attention, B=4 H=16 N=8192 D=64, b=128, m=64, T=3.
// Split-bf16 MFMA (hi+lo, 3 mfma per product) ~= fp32 precision at matrix-core rate.
// qbar/kbar/Vbar stored as packed uint32: (bf16_hi << 16) | bf16_lo.
// ws: qbar[2^25 u32] | kbar[2^25 u32] | kbar0[64*64*64 f32]. d_out doubles as Vbar.

#define BH   64
#define NTOK 8192
#define DD   64
#define MM   64
#define BBS  128

typedef __attribute__((ext_vector_type(8))) short bf16x8;
typedef __attribute__((ext_vector_type(4))) float f32x4;

__device__ __forceinline__ f32x4 MF(bf16x8 a, bf16x8 b, f32x4 c){
    return __builtin_amdgcn_mfma_f32_16x16x32_bf16(a, b, c, 0, 0, 0);
}
__device__ __forceinline__ f32x4 MF3(bf16x8 ah, bf16x8 al, bf16x8 bh_, bf16x8 bl_, f32x4 c){
    c = MF(ah, bh_, c);
    c = MF(ah, bl_, c);
    c = MF(al, bh_, c);
    return c;
}

__device__ __forceinline__ ushort bf16h(float x){
    union{float f; uint32_t u;} v; v.f = x;
    return (ushort)((v.u + 0x7fffu + ((v.u >> 16) & 1u)) >> 16);
}
__device__ __forceinline__ float bf16f(ushort h){
    union{float f; uint32_t u;} v; v.u = ((uint32_t)h) << 16; return v.f;
}
__device__ __forceinline__ void split2(float x, ushort& h, ushort& l){
    h = bf16h(x);
    l = bf16h(x - bf16f(h));
}
__device__ __forceinline__ uint32_t packsplit(float x){
    ushort h, l; split2(x, h, l);
    return ((uint32_t)h << 16) | (uint32_t)l;
}
__device__ __forceinline__ void st2(ushort* p, ushort a, ushort b){
    *(uint32_t*)p = (uint32_t)a | ((uint32_t)b << 16);
}

__device__ __forceinline__ float red16_max(float v){
    v = fmaxf(v, __shfl_xor(v, 1));
    v = fmaxf(v, __shfl_xor(v, 2));
    v = fmaxf(v, __shfl_xor(v, 4));
    v = fmaxf(v, __shfl_xor(v, 8));
    return v;
}
__device__ __forceinline__ float red16_sum(float v){
    v += __shfl_xor(v, 1);
    v += __shfl_xor(v, 2);
    v += __shfl_xor(v, 4);
    v += __shfl_xor(v, 8);
    return v;
}

// ---- Kbar0[bh][k][d] = mean over l' of K ----
__global__ __launch_bounds__(256) void kbar0_kernel(const float* __restrict__ K,
                                                    float* __restrict__ kbar0){
    const int k = blockIdx.x, bh = blockIdx.y;
    const int t = threadIdx.x;
    const int d = t & 63, p = t >> 6;
    __shared__ float part[4][64];
    const float* base = K + ((size_t)bh*NTOK + (size_t)k*BBS)*DD + d;
    float s = 0.f;
    for(int lp = p*32; lp < p*32 + 32; ++lp) s += base[(size_t)lp*DD];
    part[p][d] = s;
    __syncthreads();
    if(t < 64){
        float tot = part[0][t] + part[1][t] + part[2][t] + part[3][t];
        kbar0[((size_t)bh*MM + k)*DD + t] = tot * (1.0f/128.0f);
    }
}

// ---- L-step (MFMA): per (bh,l). S=Q Kbar^T, softmax_k -> L, Qbar = L^T Q / (w+eps) ----
__global__ __launch_bounds__(256) void l_kernel(const float* __restrict__ Q,
                                                const void* __restrict__ kb_in,
                                                int mode, uint32_t* __restrict__ qbar){
    const int l = blockIdx.x, bh = blockIdx.y;
    const int t = threadIdx.x;
    __shared__ __align__(16) ushort sQh [64*72], sQl [64*72];
    __shared__ __align__(16) ushort sQTh[64*72], sQTl[64*72];
    __shared__ __align__(16) ushort sKh [64*72], sKl [64*72];   // aliased by sLT
    __shared__ float wsum[64];
    ushort* sLTh = sKh; ushort* sLTl = sKl;

    if(t < 64) wsum[t] = 0.f;

    // stage Q (row-major + transposed), hi/lo
    #pragma unroll
    for(int j=0;j<4;++j){
        int idx = j*256 + t, i = idx >> 4, d = (idx & 15) << 2;
        float4 v = *(const float4*)(Q + ((size_t)bh*NTOK + (size_t)i*BBS + l)*DD + d);
        ushort h0,l0,h1,l1,h2,l2,h3,l3;
        split2(v.x,h0,l0); split2(v.y,h1,l1); split2(v.z,h2,l2); split2(v.w,h3,l3);
        st2(&sQh[i*72+d],   h0,h1); st2(&sQh[i*72+d+2], h2,h3);
        st2(&sQl[i*72+d],   l0,l1); st2(&sQl[i*72+d+2], l2,l3);
        sQTh[(d+0)*72+i]=h0; sQTh[(d+1)*72+i]=h1; sQTh[(d+2)*72+i]=h2; sQTh[(d+3)*72+i]=h3;
        sQTl[(d+0)*72+i]=l0; sQTl[(d+1)*72+i]=l1; sQTl[(d+2)*72+i]=l2; sQTl[(d+3)*72+i]=l3;
    }
    // stage Kbar hi/lo
    if(mode){
        const uint32_t* kp = (const uint32_t*)kb_in + ((size_t)bh*BBS + l)*(size_t)(MM*DD);
        #pragma unroll
        for(int j=0;j<8;++j){
            int f = (j*256+t)*2, k = f>>6, d = f&63;
            uint2 u = *(const uint2*)(kp + (size_t)k*DD + d);
            *(uint32_t*)&sKh[k*72+d] = (u.x >> 16)      | (u.y & 0xffff0000u);
            *(uint32_t*)&sKl[k*72+d] = (u.x & 0xffffu)  | (u.y << 16);
        }
    } else {
        const float* kp = (const float*)kb_in + (size_t)bh*(size_t)(MM*DD);
        #pragma unroll
        for(int j=0;j<4;++j){
            int idx = j*256+t, k = idx>>4, d = (idx&15)<<2;
            float4 v = *(const float4*)(kp + (size_t)k*DD + d);
            ushort h0,l0,h1,l1,h2,l2,h3,l3;
            split2(v.x,h0,l0); split2(v.y,h1,l1); split2(v.z,h2,l2); split2(v.w,h3,l3);
            st2(&sKh[k*72+d],   h0,h1); st2(&sKh[k*72+d+2], h2,h3);
            st2(&sKl[k*72+d],   l0,l1); st2(&sKl[k*72+d+2], l2,l3);
        }
    }
    __syncthreads();

    const int lane = t & 63, wv = t >> 6;
    const int n = lane & 15, qd = lane >> 4;
    const int m0 = wv * 16;

    // GEMM1: S = Q Kbar^T  (64x64, K=64)
    f32x4 accS[4] = {};
    #pragma unroll
    for(int kb=0;kb<2;++kb){
        int co = kb*32 + qd*8;
        bf16x8 ah = *(const bf16x8*)&sQh[(m0+n)*72 + co];
        bf16x8 al = *(const bf16x8*)&sQl[(m0+n)*72 + co];
        #pragma unroll
        for(int c=0;c<4;++c){
            bf16x8 bh_ = *(const bf16x8*)&sKh[(c*16+n)*72 + co];
            bf16x8 bl_ = *(const bf16x8*)&sKl[(c*16+n)*72 + co];
            accS[c] = MF3(ah, al, bh_, bl_, accS[c]);
        }
    }
    __syncthreads();   // done reading sK -> sLT may overwrite

    // softmax rows (row = m0+qd*4+r, cols c*16+n), write L^T hi/lo, col-sums
    float colp[4] = {0.f,0.f,0.f,0.f};
    #pragma unroll
    for(int r=0;r<4;++r){
        float vals[4]; float mx = -3.4e38f;
        #pragma unroll
        for(int c=0;c<4;++c){ vals[c] = accS[c][r]*0.125f; mx = fmaxf(mx, vals[c]); }
        mx = red16_max(mx);
        float s = 0.f;
        #pragma unroll
        for(int c=0;c<4;++c){ vals[c] = __expf(vals[c]-mx); s += vals[c]; }
        s = red16_sum(s);
        float inv = 1.0f/s;
        int irow = m0 + qd*4 + r;
        #pragma unroll
        for(int c=0;c<4;++c){
            float Lv = vals[c]*inv;
            colp[c] += Lv;
            ushort hh, ll; split2(Lv, hh, ll);
            sLTh[(c*16+n)*72 + irow] = hh;
            sLTl[(c*16+n)*72 + irow] = ll;
        }
    }
    #pragma unroll
    for(int c=0;c<4;++c){
        float v = colp[c];
        v += __shfl_xor(v,16); v += __shfl_xor(v,32);
        if(qd == 0) atomicAdd(&wsum[c*16+n], v);
    }
    __syncthreads();

    // GEMM2: Qbar[k][d] = sum_i L^T[k][i] Q[i][d]
    f32x4 accQ[4] = {};
    #pragma unroll
    for(int kb=0;kb<2;++kb){
        int co = kb*32 + qd*8;
        bf16x8 ah = *(const bf16x8*)&sLTh[(m0+n)*72 + co];
        bf16x8 al = *(const bf16x8*)&sLTl[(m0+n)*72 + co];
        #pragma unroll
        for(int dt2=0;dt2<4;++dt2){
            bf16x8 bh_ = *(const bf16x8*)&sQTh[(dt2*16+n)*72 + co];
            bf16x8 bl_ = *(const bf16x8*)&sQTl[(dt2*16+n)*72 + co];
            accQ[dt2] = MF3(ah, al, bh_, bl_, accQ[dt2]);
        }
    }
    uint32_t* qb = qbar + ((size_t)bh*BBS + l)*(size_t)(MM*DD);
    #pragma unroll
    for(int r=0;r<4;++r){
        int krow = m0 + qd*4 + r;
        float invw = 1.0f/(wsum[krow] + 1e-6f);
        #pragma unroll
        for(int dt2=0;dt2<4;++dt2){
            qb[(size_t)krow*DD + dt2*16 + n] = packsplit(accQ[dt2][r]*invw);
        }
    }
}

// ---- R-step (MFMA): per (bh,k), 512 thr. S=Qbar K^T (128x128), softmax_{l'} -> R,
//      Kbar = R @ K (packed to kbar) or Vbar = R @ V (packed to d_out tokens) ----
__global__ __launch_bounds__(512) void r_kernel(const uint32_t* __restrict__ qbar,
                                                const float* __restrict__ K,
                                                const float* __restrict__ V,
                                                uint32_t* __restrict__ outp, int outTok){
    const int k = blockIdx.x, bh = blockIdx.y;
    const int t = threadIdx.x;
    __shared__ __align__(16) ushort sm[54272];   // 106 KB
    ushort* sQbh = sm;            // 128*72
    ushort* sQbl = sm + 9216;
    ushort* sKh  = sm + 18432;    // 128*72
    ushort* sKl  = sm + 27648;
    ushort* sKTh = sm + 36864;    // 64*136  ((K or V) transposed)
    ushort* sKTl = sm + 45568;
    ushort* sRh  = sm;            // alias over sQb+sK after GEMM1: 128*136
    ushort* sRl  = sm + 17408;

    // stage qbar (packed) -> hi/lo
    const uint32_t* qp = qbar + (size_t)bh*BBS*(size_t)(MM*DD) + (size_t)k*DD;
    #pragma unroll
    for(int j=0;j<8;++j){
        int f = (j*512+t)*2, lq = f>>6, d = f&63;
        uint2 u = *(const uint2*)(qp + (size_t)lq*(MM*DD) + d);
        *(uint32_t*)&sQbh[lq*72+d] = (u.x >> 16)     | (u.y & 0xffff0000u);
        *(uint32_t*)&sQbl[lq*72+d] = (u.x & 0xffffu) | (u.y << 16);
    }
    // stage K rows + (K or V) transposed
    const float* kp = K + ((size_t)bh*NTOK + (size_t)k*BBS)*DD;
    const float* tp = V ? (V + ((size_t)bh*NTOK + (size_t)k*BBS)*DD) : kp;
    #pragma unroll
    for(int j=0;j<4;++j){
        int idx = j*512+t, lp = idx>>4, d = (idx&15)<<2;
        float4 v = *(const float4*)(kp + (size_t)lp*DD + d);
        ushort h0,l0,h1,l1,h2,l2,h3,l3;
        split2(v.x,h0,l0); split2(v.y,h1,l1); split2(v.z,h2,l2); split2(v.w,h3,l3);
        st2(&sKh[lp*72+d],   h0,h1); st2(&sKh[lp*72+d+2], h2,h3);
        st2(&sKl[lp*72+d],   l0,l1); st2(&sKl[lp*72+d+2], l2,l3);
        float4 w = V ? *(const float4*)(tp + (size_t)lp*DD + d) : v;
        ushort th[4], tl[4];
        split2(w.x,th[0],tl[0]); split2(w.y,th[1],tl[1]);
        split2(w.z,th[2],tl[2]); split2(w.w,th[3],tl[3]);
        #pragma unroll
        for(int r=0;r<4;++r){
            sKTh[(d+r)*136 + lp] = th[r];
            sKTl[(d+r)*136 + lp] = tl[r];
        }
    }
    __syncthreads();

    const int lane = t & 63, wv = t >> 6;   // 8 waves
    const int n = lane & 15, qd = lane >> 4;
    const int m0 = wv * 16;

    // GEMM1: S = Qbar K^T  (128x128, K-dim 64)
    f32x4 accS[8] = {};
    #pragma unroll
    for(int kb=0;kb<2;++kb){
        int co = kb*32 + qd*8;
        bf16x8 ah = *(const bf16x8*)&sQbh[(m0+n)*72 + co];
        bf16x8 al = *(const bf16x8*)&sQbl[(m0+n)*72 + co];
        #pragma unroll
        for(int c=0;c<8;++c){
            bf16x8 bh_ = *(const bf16x8*)&sKh[(c*16+n)*72 + co];
            bf16x8 bl_ = *(const bf16x8*)&sKl[(c*16+n)*72 + co];
            accS[c] = MF3(ah, al, bh_, bl_, accS[c]);
        }
    }
    __syncthreads();   // sQb/sK dead -> sR region

    // softmax rows over 128 cols; write R hi/lo row-major
    #pragma unroll
    for(int r=0;r<4;++r){
        float vals[8]; float mx = -3.4e38f;
        #pragma unroll
        for(int c=0;c<8;++c){ vals[c] = accS[c][r]*0.125f; mx = fmaxf(mx, vals[c]); }
        mx = red16_max(mx);
        float s = 0.f;
        #pragma unroll
        for(int c=0;c<8;++c){ vals[c] = __expf(vals[c]-mx); s += vals[c]; }
        s = red16_sum(s);
        float inv = 1.0f/s;
        int lrow = m0 + qd*4 + r;
        #pragma unroll
        for(int c=0;c<8;++c){
            ushort hh, ll; split2(vals[c]*inv, hh, ll);
            sRh[lrow*136 + c*16+n] = hh;
            sRl[lrow*136 + c*16+n] = ll;
        }
    }
    __syncthreads();

    // GEMM2: Out[l][d] = sum_{l'} R[l][l'] X[l'][d]   (X = K or V, via sKT)
    f32x4 accO[4] = {};
    #pragma unroll
    for(int kb=0;kb<4;++kb){
        int co = kb*32 + qd*8;
        bf16x8 ah = *(const bf16x8*)&sRh[(m0+n)*136 + co];
        bf16x8 al = *(const bf16x8*)&sRl[(m0+n)*136 + co];
        #pragma unroll
        for(int dt2=0;dt2<4;++dt2){
            bf16x8 bh_ = *(const bf16x8*)&sKTh[(dt2*16+n)*136 + co];
            bf16x8 bl_ = *(const bf16x8*)&sKTl[(dt2*16+n)*136 + co];
            accO[dt2] = MF3(ah, al, bh_, bl_, accO[dt2]);
        }
    }
    #pragma unroll
    for(int r=0;r<4;++r){
        int lrow = m0 + qd*4 + r;
        #pragma unroll
        for(int dt2=0;dt2<4;++dt2){
            uint32_t pw = packsplit(accO[dt2][r]);
            size_t off = outTok
                ? ((size_t)bh*NTOK + (size_t)k*BBS + lrow)*DD + dt2*16 + n
                : (((size_t)bh*BBS + lrow)*(size_t)MM + k)*DD + dt2*16 + n;
            outp[off] = pw;
        }
    }
}

// ---- Out (MFMA): per (bh,l). Recompute L3 from (Q,Kbar2); out = L3 @ Vbar ----
__global__ __launch_bounds__(256) void out_kernel(const float* __restrict__ Q,
                                                  const uint32_t* __restrict__ kbar,
                                                  float* __restrict__ out){
    const int l = blockIdx.x, bh = blockIdx.y;
    const int t = threadIdx.x;
    __shared__ __align__(16) ushort sQh [64*72], sQl [64*72];
    __shared__ __align__(16) ushort sKh [64*72], sKl [64*72];   // aliased by sL
    __shared__ __align__(16) ushort sVTh[64*72], sVTl[64*72];
    ushort* sLh = sKh; ushort* sLl = sKl;

    // stage Q rows
    #pragma unroll
    for(int j=0;j<4;++j){
        int idx = j*256+t, i = idx>>4, d = (idx&15)<<2;
        float4 v = *(const float4*)(Q + ((size_t)bh*NTOK + (size_t)i*BBS + l)*DD + d);
        ushort h0,l0,h1,l1,h2,l2,h3,l3;
        split2(v.x,h0,l0); split2(v.y,h1,l1); split2(v.z,h2,l2); split2(v.w,h3,l3);
        st2(&sQh[i*72+d],   h0,h1); st2(&sQh[i*72+d+2], h2,h3);
        st2(&sQl[i*72+d],   l0,l1); st2(&sQl[i*72+d+2], l2,l3);
    }
    // stage Kbar (packed)
    const uint32_t* kp = kbar + ((size_t)bh*BBS + l)*(size_t)(MM*DD);
    #pragma unroll
    for(int j=0;j<8;++j){
        int f = (j*256+t)*2, k = f>>6, d = f&63;
        uint2 u = *(const uint2*)(kp + (size_t)k*DD + d);
        *(uint32_t*)&sKh[k*72+d] = (u.x >> 16)     | (u.y & 0xffff0000u);
        *(uint32_t*)&sKl[k*72+d] = (u.x & 0xffffu) | (u.y << 16);
    }
    // stage Vbar (packed in d_out at tokens kk*b + l), transposed
    const uint32_t* vb = (const uint32_t*)out;
    #pragma unroll
    for(int j=0;j<16;++j){
        int idx = j*256+t, kk = idx>>6, d = idx&63;
        uint32_t u = vb[((size_t)bh*NTOK + (size_t)kk*BBS + l)*DD + d];
        sVTh[d*72+kk] = (ushort)(u >> 16);
        sVTl[d*72+kk] = (ushort)(u & 0xffffu);
    }
    __syncthreads();

    const int lane = t & 63, wv = t >> 6;
    const int n = lane & 15, qd = lane >> 4;
    const int m0 = wv * 16;

    // GEMM1: S = Q Kbar^T
    f32x4 accS[4] = {};
    #pragma unroll
    for(int kb=0;kb<2;++kb){
        int co = kb*32 + qd*8;
        bf16x8 ah = *(const bf16x8*)&sQh[(m0+n)*72 + co];
        bf16x8 al = *(const bf16x8*)&sQl[(m0+n)*72 + co];
        #pragma unroll
        for(int c=0;c<4;++c){
            bf16x8 bh_ = *(const bf16x8*)&sKh[(c*16+n)*72 + co];
            bf16x8 bl_ = *(const bf16x8*)&sKl[(c*16+n)*72 + co];
            accS[c] = MF3(ah, al, bh_, bl_, accS[c]);
        }
    }
    __syncthreads();   // done reading sK -> sL may overwrite

    // softmax -> L row-major hi/lo
    #pragma unroll
    for(int r=0;r<4;++r){
        float vals[4]; float mx = -3.4e38f;
        #pragma unroll
        for(int c=0;c<4;++c){ vals[c] = accS[c][r]*0.125f; mx = fmaxf(mx, vals[c]); }
        mx = red16_max(mx);
        float s = 0.f;
        #pragma unroll
        for(int c=0;c<4;++c){ vals[c] = __expf(vals[c]-mx); s += vals[c]; }
        s = red16_sum(s);
        float inv = 1.0f/s;
        int irow = m0 + qd*4 + r;
        #pragma unroll
        for(int c=0;c<4;++c){
            ushort hh, ll; split2(vals[c]*inv, hh, ll);
            sLh[irow*72 + c*16+n] = hh;
            sLl[irow*72 + c*16+n] = ll;
        }
    }
    __syncthreads();

    // GEMM2: O[i][d] = sum_k L[i][k] Vbar[k][d]
    f32x4 accO[4] = {};
    #pragma unroll
    for(int kb=0;kb<2;++kb){
        int co = kb*32 + qd*8;
        bf16x8 ah = *(const bf16x8*)&sLh[(m0+n)*72 + co];
        bf16x8 al = *(const bf16x8*)&sLl[(m0+n)*72 + co];
        #pragma unroll
        for(int dt2=0;dt2<4;++dt2){
            bf16x8 bh_ = *(const bf16x8*)&sVTh[(dt2*16+n)*72 + co];
            bf16x8 bl_ = *(const bf16x8*)&sVTl[(dt2*16+n)*72 + co];
            accO[dt2] = MF3(ah, al, bh_, bl_, accO[dt2]);
        }
    }
    #pragma unroll
    for(int r=0;r<4;++r){
        int irow = m0 + qd*4 + r;
        #pragma unroll
        for(int dt2=0;dt2<4;++dt2){
            out[((size_t)bh*NTOK + (size_t)irow*BBS + l)*DD + dt2*16 + n] = accO[dt2][r];
        }
    }
}

extern "C" void kernel_launch(void* const* d_in, const int* in_sizes, int n_in,
                              void* d_out, int out_size, void* d_ws, size_t ws_size,
                              hipStream_t stream){
    const float* Q = (const float*)d_in[0];
    const float* K = (const float*)d_in[1];
    const float* V = (const float*)d_in[2];
    float* out = (float*)d_out;
    const size_t big = (size_t)BH * BBS * MM * DD;     // 33,554,432
    uint32_t* qbar  = (uint32_t*)d_ws;
    uint32_t* kbar  = qbar + big;
    float*    kbar0 = (float*)(kbar + big);            // ~257 MiB total

    kbar0_kernel<<<dim3(MM, BH), 256, 0, stream>>>(K, kbar0);
    // step 0
    l_kernel<<<dim3(BBS, BH), 256, 0, stream>>>(Q, kbar0, 0, qbar);
    r_kernel<<<dim3(MM, BH), 512, 0, stream>>>(qbar, K, nullptr, kbar, 0);
    // step 1
    l_kernel<<<dim3(BBS, BH), 256, 0, stream>>>(Q, kbar, 1, qbar);
    r_kernel<<<dim3(MM, BH), 512, 0, stream>>>(qbar, K, nullptr, kbar, 0);
    // step 2
    l_kernel<<<dim3(BBS, BH), 256, 0, stream>>>(Q, kbar, 1, qbar);
    r_kernel<<<dim3(MM, BH), 512, 0, stream>>>(qbar, K, V, (uint32_t*)out, 1);  // Vbar
    // epilogue: recompute L3, out = L3 @ Vbar
    out_kernel<<<dim3(BBS, BH), 256, 0, stream>>>(Q, kbar, out);
}